// Round 1
// baseline (290.359 us; speedup 1.0000x reference)
//
#include <hip/hip_runtime.h>
#include <stdint.h>

typedef float f32x4 __attribute__((ext_vector_type(4)));
typedef __bf16 bf16x8 __attribute__((ext_vector_type(8)));

#define LOG2E 1.4426950408889634f
#define SCL2 (0.125f * LOG2E)   // 1/sqrt(64) folded with log2(e) for exp2

// RNE float -> bf16 bits (values are finite; NaN path not needed)
static __device__ __forceinline__ unsigned short f2bf(float f) {
  unsigned int u = __builtin_bit_cast(unsigned int, f);
  u += 0x7fffu + ((u >> 16) & 1u);
  return (unsigned short)(u >> 16);
}

static __device__ __forceinline__ void gload16(const void* g, void* l) {
  __builtin_amdgcn_global_load_lds(
      (const __attribute__((address_space(1))) unsigned int*)g,
      (__attribute__((address_space(3))) unsigned int*)l, 16, 0, 0);
}

// ---------------- kernel 1: x fp32 -> bf16 ----------------
__global__ void cvt_x_kernel(const float* __restrict__ x, unsigned short* __restrict__ xb) {
  size_t i = ((size_t)blockIdx.x * 256 + threadIdx.x) * 8;
  const float4 a = *(const float4*)(x + i);
  const float4 b = *(const float4*)(x + i + 4);
  union { unsigned short us[8]; uint4 u; } o;
  o.us[0] = f2bf(a.x); o.us[1] = f2bf(a.y); o.us[2] = f2bf(a.z); o.us[3] = f2bf(a.w);
  o.us[4] = f2bf(b.x); o.us[5] = f2bf(b.y); o.us[6] = f2bf(b.z); o.us[7] = f2bf(b.w);
  *(uint4*)(xb + i) = o.u;
}

// ---------------- kernel 2: W [k][n] fp32 -> Wt [n][k] bf16 (x3) ----------------
__global__ void wt_kernel(const float* __restrict__ Wq, const float* __restrict__ Wk,
                          const float* __restrict__ Wv, unsigned short* __restrict__ Wt) {
  __shared__ float t[32][33];
  const int z = blockIdx.z;
  const float* W = (z == 0) ? Wq : ((z == 1) ? Wk : Wv);
  unsigned short* o = Wt + (size_t)z * 1048576;
  const int k0 = blockIdx.y * 32, n0 = blockIdx.x * 32;
  const int tx = threadIdx.x, ty = threadIdx.y;
#pragma unroll
  for (int i = 0; i < 4; ++i)
    t[ty + i * 8][tx] = W[(size_t)(k0 + ty + i * 8) * 1024 + n0 + tx];
  __syncthreads();
#pragma unroll
  for (int i = 0; i < 4; ++i)
    o[(size_t)(n0 + ty + i * 8) * 1024 + k0 + tx] = f2bf(t[tx][ty + i * 8]);
}

// ---------------- kernel 3: QKV GEMM (m97 structure) ----------------
// C[m][n] = sum_k xb[m][k] * Wt[n][k]; 128x128 tile, BK=32, 4 waves (2x2 of 64x64).
// z=0 -> Q [bh][t][64], z=1 -> K [bh][t][64], z=2 -> Vt [bh][64][t]  (all bf16)
__global__ __launch_bounds__(256) void gemm_qkv(
    const unsigned short* __restrict__ xb, const unsigned short* __restrict__ Wt,
    unsigned short* __restrict__ Qb, unsigned short* __restrict__ Kb,
    unsigned short* __restrict__ Vtb) {
  __shared__ uint4 ldsab[1024];  // 16KB: A [0,8192), B [8192,16384)
  char* ldsc = (char*)ldsab;
  const int tid = threadIdx.x;
  const int lane = tid & 63;
  const int li = lane & 15, g = lane >> 4;
  const int wv = tid >> 6, wr = wv >> 1, wc = wv & 1;
  const int z = blockIdx.z;
  const int m0 = blockIdx.y * 128, n0 = blockIdx.x * 128;
  const char* Abase = (const char*)xb;
  const char* Bbase = (const char*)(Wt + (size_t)z * 1048576);

  const f32x4 fz = {0.f, 0.f, 0.f, 0.f};
  f32x4 acc[4][4];
#pragma unroll
  for (int m = 0; m < 4; ++m)
#pragma unroll
    for (int n = 0; n < 4; ++n) acc[m][n] = fz;

  for (int kt = 0; kt < 32; ++kt) {
    __syncthreads();  // previous compute done reading LDS
#pragma unroll
    for (int i = 0; i < 2; ++i) {
      const int c = i * 256 + tid;
      gload16(Abase + (size_t)(m0 + (c >> 2)) * 2048 + kt * 64 + (c & 3) * 16,
              ldsc + c * 16);
      gload16(Bbase + (size_t)(n0 + (c >> 2)) * 2048 + kt * 64 + (c & 3) * 16,
              ldsc + 8192 + c * 16);
    }
    __syncthreads();  // vmcnt(0) drained -> LDS ready
    bf16x8 a[4], b[4];
#pragma unroll
    for (int m = 0; m < 4; ++m)
      a[m] = *(const bf16x8*)(ldsc + ((wr * 64 + m * 16 + li) * 64 + g * 16));
#pragma unroll
    for (int n = 0; n < 4; ++n)
      b[n] = *(const bf16x8*)(ldsc + 8192 + ((wc * 64 + n * 16 + li) * 64 + g * 16));
#pragma unroll
    for (int m = 0; m < 4; ++m)
#pragma unroll
      for (int n = 0; n < 4; ++n)
        acc[m][n] = __builtin_amdgcn_mfma_f32_16x16x32_bf16(a[m], b[n], acc[m][n], 0, 0, 0);
  }

  unsigned short* dst = (z == 0) ? Qb : ((z == 1) ? Kb : Vtb);
#pragma unroll
  for (int m = 0; m < 4; ++m) {
#pragma unroll
    for (int r = 0; r < 4; ++r) {
      const int mg = m0 + wr * 64 + m * 16 + g * 4 + r;
      const int bI = mg >> 11, t = mg & 2047;
#pragma unroll
      for (int n = 0; n < 4; ++n) {
        const int ng = n0 + wc * 64 + n * 16 + li;
        const int h = ng >> 6, d = ng & 63;
        const unsigned short v = f2bf(acc[m][n][r]);
        if (z == 2)
          dst[((size_t)(bI * 16 + h) * 64 + d) * 2048 + t] = v;
        else
          dst[((size_t)(bI * 16 + h) * 2048 + t) * 64 + d] = v;
      }
    }
  }
}

// ---------------- kernel 4: causal flash attention ----------------
// grid (16 qtiles, 64 bh); 4 waves x 32 q-rows; KV tile = 64.
// S^T = K . Q^T  (lane owns q = col);  PV uses pi-permuted contraction so the
// P fragment is the lane's own 8 probs (zero cross-lane exchange).
__global__ __launch_bounds__(256) void attn_kernel(
    const unsigned short* __restrict__ Qb, const unsigned short* __restrict__ Kb,
    const unsigned short* __restrict__ Vtb, float* __restrict__ out) {
  __shared__ uint4 lds[3072];  // 48KB: K [0,8K), Vt [8K,16K), trb [16K,48K)
  char* ldsc = (char*)lds;
  const int qt = blockIdx.x, bh = blockIdx.y;
  const int tid = threadIdx.x;
  const int lane = tid & 63, wv = tid >> 6;
  const int li = lane & 15, g = lane >> 4;
  const int q0 = qt * 128;
  const int qw = q0 + wv * 32;

  const char* Qrow = (const char*)Qb + (size_t)bh * 2048 * 128;
  const char* Krow = (const char*)Kb + (size_t)bh * 2048 * 128;
  const char* Vrow = (const char*)Vtb + (size_t)bh * 64 * 4096;

  // Q fragments (B-operand of S^T): qf[nq][ks] = Q[qw+nq*16+li][ks*32+g*8 .. +8]
  uint4 qf[2][2];
#pragma unroll
  for (int nq = 0; nq < 2; ++nq)
#pragma unroll
    for (int ks = 0; ks < 2; ++ks)
      qf[nq][ks] = *(const uint4*)(Qrow + (size_t)(qw + nq * 16 + li) * 128 + ks * 64 + g * 16);

  const f32x4 fz = {0.f, 0.f, 0.f, 0.f};
  float mrow[2] = {-1e30f, -1e30f};
  float lrow[2] = {0.0f, 0.0f};
  f32x4 ctx[4][2];
#pragma unroll
  for (int mtd = 0; mtd < 4; ++mtd)
#pragma unroll
    for (int nq = 0; nq < 2; ++nq) ctx[mtd][nq] = fz;

  const int nkt = qt * 2 + 2;
  for (int kt = 0; kt < nkt; ++kt) {
    // stage K tile [64][64] and Vt tile [64 d][64 t] with 16B-chunk XOR swizzle
    uint4 kreg[2], vreg[2];
#pragma unroll
    for (int i = 0; i < 2; ++i) {
      const int c = i * 256 + tid, r = c >> 3, cr = c & 7;
      kreg[i] = *(const uint4*)(Krow + (size_t)(kt * 64 + r) * 128 + cr * 16);
      vreg[i] = *(const uint4*)(Vrow + (size_t)r * 4096 + kt * 128 + cr * 16);
    }
    __syncthreads();
#pragma unroll
    for (int i = 0; i < 2; ++i) {
      const int c = i * 256 + tid, r = c >> 3, cr = c & 7;
      *(uint4*)(ldsc + r * 128 + ((cr ^ (r & 7)) * 16)) = kreg[i];
      *(uint4*)(ldsc + 8192 + r * 128 + ((cr ^ (r & 7)) * 16)) = vreg[i];
    }
    __syncthreads();
    if (kt * 64 > qw + 31) continue;  // fully masked for this wave (barriers stay uniform)

    // ---- S^T = K . Q^T : rows kk (4 x 16), cols q (2 x 16) ----
    f32x4 st[4][2];
#pragma unroll
    for (int mt = 0; mt < 4; ++mt)
#pragma unroll
      for (int nq = 0; nq < 2; ++nq) st[mt][nq] = fz;
#pragma unroll
    for (int ks = 0; ks < 2; ++ks) {
      bf16x8 kf[4];
#pragma unroll
      for (int mt = 0; mt < 4; ++mt) {
        const int rk = mt * 16 + li;
        kf[mt] = *(const bf16x8*)(ldsc + rk * 128 + (((ks * 4 + g) ^ (rk & 7)) * 16));
      }
#pragma unroll
      for (int mt = 0; mt < 4; ++mt)
#pragma unroll
        for (int nq = 0; nq < 2; ++nq)
          st[mt][nq] = __builtin_amdgcn_mfma_f32_16x16x32_bf16(
              kf[mt], __builtin_bit_cast(bf16x8, qf[nq][ks]), st[mt][nq], 0, 0, 0);
    }

    // ---- online softmax (per lane: q = qw + nq*16 + li; kk = kt*64+mt*16+g*4+r) ----
    const bool full = (kt * 64 + 63 <= qw);
    bf16x8 pb[2][2];
#pragma unroll
    for (int nq = 0; nq < 2; ++nq) {
      const int qg_ = qw + nq * 16 + li;
      float p[4][4];
      float tmax = -__builtin_inff();
#pragma unroll
      for (int mt = 0; mt < 4; ++mt)
#pragma unroll
        for (int r = 0; r < 4; ++r) {
          float v = st[mt][nq][r] * SCL2;
          if (!full && (kt * 64 + mt * 16 + g * 4 + r > qg_)) v = -__builtin_inff();
          p[mt][r] = v;
          tmax = fmaxf(tmax, v);
        }
      tmax = fmaxf(tmax, __shfl_xor(tmax, 16, 64));
      tmax = fmaxf(tmax, __shfl_xor(tmax, 32, 64));
      const float mnew = fmaxf(mrow[nq], tmax);
      const float resc = __builtin_amdgcn_exp2f(mrow[nq] - mnew);
      mrow[nq] = mnew;
      float psum = 0.0f;
#pragma unroll
      for (int mt = 0; mt < 4; ++mt)
#pragma unroll
        for (int r = 0; r < 4; ++r) {
          const float e = __builtin_amdgcn_exp2f(p[mt][r] - mnew);
          p[mt][r] = e;
          psum += e;
        }
      psum += __shfl_xor(psum, 16, 64);
      psum += __shfl_xor(psum, 32, 64);
      lrow[nq] = lrow[nq] * resc + psum;
#pragma unroll
      for (int mtd = 0; mtd < 4; ++mtd) ctx[mtd][nq] = ctx[mtd][nq] * resc;
      // pack P for PV: frag(ks2) = {p[2ks2][0..3], p[2ks2+1][0..3]}
#pragma unroll
      for (int ks2 = 0; ks2 < 2; ++ks2) {
        union { unsigned short us[8]; bf16x8 v; } u;
#pragma unroll
        for (int r = 0; r < 4; ++r) {
          u.us[r] = f2bf(p[2 * ks2][r]);
          u.us[4 + r] = f2bf(p[2 * ks2 + 1][r]);
        }
        pb[nq][ks2] = u.v;
      }
    }

    // ---- PV: ctx^T[d][q] += Vt . P^T  (pi-permuted k; A = 2x ds_read_b64) ----
#pragma unroll
    for (int ks2 = 0; ks2 < 2; ++ks2)
#pragma unroll
      for (int mtd = 0; mtd < 4; ++mtd) {
        const int rd = mtd * 16 + li;
        const char* vb = ldsc + 8192 + rd * 128;
        const uint2 lo = *(const uint2*)(vb + (((ks2 * 4 + (g >> 1)) ^ (rd & 7)) * 16) + (g & 1) * 8);
        const uint2 hi = *(const uint2*)(vb + (((ks2 * 4 + 2 + (g >> 1)) ^ (rd & 7)) * 16) + (g & 1) * 8);
        uint4 vv; vv.x = lo.x; vv.y = lo.y; vv.z = hi.x; vv.w = hi.y;
        const bf16x8 vf = __builtin_bit_cast(bf16x8, vv);
#pragma unroll
        for (int nq = 0; nq < 2; ++nq)
          ctx[mtd][nq] = __builtin_amdgcn_mfma_f32_16x16x32_bf16(vf, pb[nq][ks2], ctx[mtd][nq], 0, 0, 0);
      }
  }

  // ---- epilogue: ctx^T -> ctx via per-wave swizzled LDS, coalesced f32 stores ----
  __syncthreads();
  float* trb = (float*)(ldsc + 16384 + wv * 8192);
#pragma unroll
  for (int nq = 0; nq < 2; ++nq) {
    const float inv = 1.0f / lrow[nq];
    const int q = nq * 16 + li;
#pragma unroll
    for (int mtd = 0; mtd < 4; ++mtd)
#pragma unroll
      for (int r = 0; r < 4; ++r) {
        const int d = mtd * 16 + g * 4 + r;
        trb[q * 64 + ((((d >> 2) ^ (q & 15)) << 2) | (d & 3))] = ctx[mtd][nq][r] * inv;
      }
  }
  __syncthreads();
  const int bI = bh >> 4, h = bh & 15;
#pragma unroll
  for (int pass = 0; pass < 8; ++pass) {
    const int qr = pass * 4 + g;
    const float4 v = *(const float4*)&trb[qr * 64 + ((li ^ (qr & 15)) << 2)];
    *(float4*)(out + ((size_t)bI * 2048 + q0 + wv * 32 + qr) * 1024 + h * 64 + li * 4) = v;
  }
}

// ---------------- launcher ----------------
extern "C" void kernel_launch(void* const* d_in, const int* in_sizes, int n_in,
                              void* d_out, int out_size, void* d_ws, size_t ws_size,
                              hipStream_t stream) {
  (void)in_sizes; (void)n_in; (void)out_size; (void)ws_size;
  const float* x  = (const float*)d_in[0];
  const float* Wq = (const float*)d_in[1];
  const float* Wk = (const float*)d_in[2];
  const float* Wv = (const float*)d_in[3];
  float* out = (float*)d_out;
  char* ws = (char*)d_ws;
  unsigned short* xb  = (unsigned short*)ws;                    // 8192x1024 bf16  (16 MB)
  unsigned short* Wt  = (unsigned short*)(ws + 16777216);       // 3x 1024x1024 bf16 (6 MB)
  unsigned short* Qb  = (unsigned short*)(ws + 23068672);       // [64][2048][64] bf16
  unsigned short* Kb  = (unsigned short*)(ws + 39845888);       // [64][2048][64] bf16
  unsigned short* Vtb = (unsigned short*)(ws + 56623104);       // [64][64][2048] bf16

  hipLaunchKernelGGL(cvt_x_kernel, dim3(4096), dim3(256), 0, stream, x, xb);
  hipLaunchKernelGGL(wt_kernel, dim3(32, 32, 3), dim3(32, 8), 0, stream, Wq, Wk, Wv, Wt);
  hipLaunchKernelGGL(gemm_qkv, dim3(8, 64, 3), dim3(256), 0, stream, xb, Wt, Qb, Kb, Vtb);
  hipLaunchKernelGGL(attn_kernel, dim3(16, 64), dim3(256), 0, stream, Qb, Kb, Vtb, out);
}

// Round 2
// 239.016 us; speedup vs baseline: 1.2148x; 1.2148x over previous
//
#include <hip/hip_runtime.h>
#include <stdint.h>

typedef float f32x4 __attribute__((ext_vector_type(4)));
typedef __bf16 bf16x8 __attribute__((ext_vector_type(8)));

#define LOG2E 1.4426950408889634f
#define SCL2 (0.125f * LOG2E)   // 1/sqrt(64) * log2(e), folded into Q at GEMM epilogue

// RNE float -> bf16 bits (values are finite; NaN path not needed)
static __device__ __forceinline__ unsigned short f2bf(float f) {
  unsigned int u = __builtin_bit_cast(unsigned int, f);
  u += 0x7fffu + ((u >> 16) & 1u);
  return (unsigned short)(u >> 16);
}

static __device__ __forceinline__ void gload16(const void* g, void* l) {
  __builtin_amdgcn_global_load_lds(
      (const __attribute__((address_space(1))) unsigned int*)g,
      (__attribute__((address_space(3))) unsigned int*)l, 16, 0, 0);
}

// ---------------- kernel 1: x fp32 -> bf16 ----------------
__global__ void cvt_x_kernel(const float* __restrict__ x, unsigned short* __restrict__ xb) {
  size_t i = ((size_t)blockIdx.x * 256 + threadIdx.x) * 8;
  const float4 a = *(const float4*)(x + i);
  const float4 b = *(const float4*)(x + i + 4);
  union { unsigned short us[8]; uint4 u; } o;
  o.us[0] = f2bf(a.x); o.us[1] = f2bf(a.y); o.us[2] = f2bf(a.z); o.us[3] = f2bf(a.w);
  o.us[4] = f2bf(b.x); o.us[5] = f2bf(b.y); o.us[6] = f2bf(b.z); o.us[7] = f2bf(b.w);
  *(uint4*)(xb + i) = o.u;
}

// ---------------- kernel 2: W [k][n] fp32 -> Wt [n][k] bf16 (x3) ----------------
__global__ void wt_kernel(const float* __restrict__ Wq, const float* __restrict__ Wk,
                          const float* __restrict__ Wv, unsigned short* __restrict__ Wt) {
  __shared__ float t[32][33];
  const int z = blockIdx.z;
  const float* W = (z == 0) ? Wq : ((z == 1) ? Wk : Wv);
  unsigned short* o = Wt + (size_t)z * 1048576;
  const int k0 = blockIdx.y * 32, n0 = blockIdx.x * 32;
  const int tx = threadIdx.x, ty = threadIdx.y;
#pragma unroll
  for (int i = 0; i < 4; ++i)
    t[ty + i * 8][tx] = W[(size_t)(k0 + ty + i * 8) * 1024 + n0 + tx];
  __syncthreads();
#pragma unroll
  for (int i = 0; i < 4; ++i)
    o[(size_t)(n0 + ty + i * 8) * 1024 + k0 + tx] = f2bf(t[tx][ty + i * 8]);
}

// ---------------- kernel 3: QKV GEMM (m97 structure) ----------------
// C[m][n] = sum_k xb[m][k] * Wt[n][k]; 128x128 tile, BK=32, 4 waves (2x2 of 64x64).
// z=0 -> Q [bh][t][64] (pre-scaled by SCL2), z=1 -> K [bh][t][64], z=2 -> Vt [bh][64][t]
__global__ __launch_bounds__(256) void gemm_qkv(
    const unsigned short* __restrict__ xb, const unsigned short* __restrict__ Wt,
    unsigned short* __restrict__ Qb, unsigned short* __restrict__ Kb,
    unsigned short* __restrict__ Vtb) {
  __shared__ uint4 ldsab[1024];  // 16KB: A [0,8192), B [8192,16384)
  char* ldsc = (char*)ldsab;
  const int tid = threadIdx.x;
  const int lane = tid & 63;
  const int li = lane & 15, g = lane >> 4;
  const int wv = tid >> 6, wr = wv >> 1, wc = wv & 1;
  const int z = blockIdx.z;
  const int m0 = blockIdx.y * 128, n0 = blockIdx.x * 128;
  const char* Abase = (const char*)xb;
  const char* Bbase = (const char*)(Wt + (size_t)z * 1048576);

  const f32x4 fz = {0.f, 0.f, 0.f, 0.f};
  f32x4 acc[4][4];
#pragma unroll
  for (int m = 0; m < 4; ++m)
#pragma unroll
    for (int n = 0; n < 4; ++n) acc[m][n] = fz;

  for (int kt = 0; kt < 32; ++kt) {
    __syncthreads();  // previous compute done reading LDS
#pragma unroll
    for (int i = 0; i < 2; ++i) {
      const int c = i * 256 + tid;
      gload16(Abase + (size_t)(m0 + (c >> 2)) * 2048 + kt * 64 + (c & 3) * 16,
              ldsc + c * 16);
      gload16(Bbase + (size_t)(n0 + (c >> 2)) * 2048 + kt * 64 + (c & 3) * 16,
              ldsc + 8192 + c * 16);
    }
    __syncthreads();  // vmcnt(0) drained -> LDS ready
    bf16x8 a[4], b[4];
#pragma unroll
    for (int m = 0; m < 4; ++m)
      a[m] = *(const bf16x8*)(ldsc + ((wr * 64 + m * 16 + li) * 64 + g * 16));
#pragma unroll
    for (int n = 0; n < 4; ++n)
      b[n] = *(const bf16x8*)(ldsc + 8192 + ((wc * 64 + n * 16 + li) * 64 + g * 16));
#pragma unroll
    for (int m = 0; m < 4; ++m)
#pragma unroll
      for (int n = 0; n < 4; ++n)
        acc[m][n] = __builtin_amdgcn_mfma_f32_16x16x32_bf16(a[m], b[n], acc[m][n], 0, 0, 0);
  }

  unsigned short* dst = (z == 0) ? Qb : ((z == 1) ? Kb : Vtb);
  const float sc = (z == 0) ? SCL2 : 1.0f;
#pragma unroll
  for (int m = 0; m < 4; ++m) {
#pragma unroll
    for (int r = 0; r < 4; ++r) {
      const int mg = m0 + wr * 64 + m * 16 + g * 4 + r;
      const int bI = mg >> 11, t = mg & 2047;
#pragma unroll
      for (int n = 0; n < 4; ++n) {
        const int ng = n0 + wc * 64 + n * 16 + li;
        const int h = ng >> 6, d = ng & 63;
        const unsigned short v = f2bf(acc[m][n][r] * sc);
        if (z == 2)
          dst[((size_t)(bI * 16 + h) * 64 + d) * 2048 + t] = v;
        else
          dst[((size_t)(bI * 16 + h) * 2048 + t) * 64 + d] = v;
      }
    }
  }
}

// ---------------- kernel 4: causal flash attention ----------------
// grid (8 qtile-pairs, 64 bh); each block does q-tiles {bx, 15-bx} -> uniform
// 34 KV iterations per block (no causal tail). 4 waves x 32 q-rows; KV tile 64.
// S^T = K . Q^T (lane owns q = col); PV uses pi-permuted contraction so the
// P fragment is the lane's own 8 probs (zero cross-lane exchange).
__global__ __launch_bounds__(256) void attn_kernel(
    const unsigned short* __restrict__ Qb, const unsigned short* __restrict__ Kb,
    const unsigned short* __restrict__ Vtb, float* __restrict__ out) {
  __shared__ uint4 lds[2048];  // 32KB: K [0,8K), Vt [8K,16K); epilogue trb reuses [0,32K)
  char* ldsc = (char*)lds;
  const int bh = blockIdx.y;
  const int tid = threadIdx.x;
  const int lane = tid & 63, wv = tid >> 6;
  const int li = lane & 15, g = lane >> 4;

  const char* Qrow = (const char*)Qb + (size_t)bh * 2048 * 128;
  const char* Krow = (const char*)Kb + (size_t)bh * 2048 * 128;
  const char* Vrow = (const char*)Vtb + (size_t)bh * 64 * 4096;
  const int bI = bh >> 4, h = bh & 15;
  const f32x4 fz = {0.f, 0.f, 0.f, 0.f};

  for (int half = 0; half < 2; ++half) {
    const int qt = half ? (15 - blockIdx.x) : blockIdx.x;
    const int q0 = qt * 128;
    const int qw = q0 + wv * 32;

    // Q fragments (B-operand of S^T): qf[nq][ks] = Q[qw+nq*16+li][ks*32+g*8 .. +8]
    uint4 qf[2][2];
#pragma unroll
    for (int nq = 0; nq < 2; ++nq)
#pragma unroll
      for (int ks = 0; ks < 2; ++ks)
        qf[nq][ks] = *(const uint4*)(Qrow + (size_t)(qw + nq * 16 + li) * 128 + ks * 64 + g * 16);

    float mrow[2] = {-1e30f, -1e30f};
    float lrow[2] = {0.0f, 0.0f};
    f32x4 ctx[4][2];
#pragma unroll
    for (int mtd = 0; mtd < 4; ++mtd)
#pragma unroll
      for (int nq = 0; nq < 2; ++nq) ctx[mtd][nq] = fz;

    const int nkt = qt * 2 + 2;
    for (int kt = 0; kt < nkt; ++kt) {
      // stage K tile [64][64] and Vt tile [64 d][64 t] with 16B-chunk XOR swizzle
      uint4 kreg[2], vreg[2];
#pragma unroll
      for (int i = 0; i < 2; ++i) {
        const int c = i * 256 + tid, r = c >> 3, cr = c & 7;
        kreg[i] = *(const uint4*)(Krow + (size_t)(kt * 64 + r) * 128 + cr * 16);
        vreg[i] = *(const uint4*)(Vrow + (size_t)r * 4096 + kt * 128 + cr * 16);
      }
      __syncthreads();
#pragma unroll
      for (int i = 0; i < 2; ++i) {
        const int c = i * 256 + tid, r = c >> 3, cr = c & 7;
        *(uint4*)(ldsc + r * 128 + ((cr ^ (r & 7)) * 16)) = kreg[i];
        *(uint4*)(ldsc + 8192 + r * 128 + ((cr ^ (r & 7)) * 16)) = vreg[i];
      }
      __syncthreads();
      if (kt * 64 > qw + 31) continue;  // fully masked for this wave (barriers stay uniform)

      // ---- S^T = K . Q^T : rows kk (4 x 16), cols q (2 x 16) ----
      f32x4 st[4][2];
#pragma unroll
      for (int mt = 0; mt < 4; ++mt)
#pragma unroll
        for (int nq = 0; nq < 2; ++nq) st[mt][nq] = fz;
#pragma unroll
      for (int ks = 0; ks < 2; ++ks) {
        bf16x8 kf[4];
#pragma unroll
        for (int mt = 0; mt < 4; ++mt) {
          const int rk = mt * 16 + li;
          kf[mt] = *(const bf16x8*)(ldsc + rk * 128 + (((ks * 4 + g) ^ (rk & 7)) * 16));
        }
#pragma unroll
        for (int mt = 0; mt < 4; ++mt)
#pragma unroll
          for (int nq = 0; nq < 2; ++nq)
            st[mt][nq] = __builtin_amdgcn_mfma_f32_16x16x32_bf16(
                kf[mt], __builtin_bit_cast(bf16x8, qf[nq][ks]), st[mt][nq], 0, 0, 0);
      }

      // ---- online softmax; Q was pre-scaled by 1/sqrt(d)*log2e, use exp2 ----
      const bool full = (kt * 64 + 63 <= qw);
      bf16x8 pb[2][2];
#pragma unroll
      for (int nq = 0; nq < 2; ++nq) {
        float p[4][4];
        if (full) {
#pragma unroll
          for (int mt = 0; mt < 4; ++mt)
#pragma unroll
            for (int r = 0; r < 4; ++r) p[mt][r] = st[mt][nq][r];
        } else {
          const int qg_ = qw + nq * 16 + li;
#pragma unroll
          for (int mt = 0; mt < 4; ++mt)
#pragma unroll
            for (int r = 0; r < 4; ++r)
              p[mt][r] = (kt * 64 + mt * 16 + g * 4 + r > qg_) ? -__builtin_inff()
                                                               : st[mt][nq][r];
        }
        // max tree (pairwise -> compiler can fuse to max3)
        float a0 = fmaxf(fmaxf(p[0][0], p[0][1]), fmaxf(p[0][2], p[0][3]));
        float a1 = fmaxf(fmaxf(p[1][0], p[1][1]), fmaxf(p[1][2], p[1][3]));
        float a2 = fmaxf(fmaxf(p[2][0], p[2][1]), fmaxf(p[2][2], p[2][3]));
        float a3 = fmaxf(fmaxf(p[3][0], p[3][1]), fmaxf(p[3][2], p[3][3]));
        float tmax = fmaxf(fmaxf(a0, a1), fmaxf(a2, a3));
        tmax = fmaxf(tmax, __shfl_xor(tmax, 16, 64));
        tmax = fmaxf(tmax, __shfl_xor(tmax, 32, 64));
        // defer-max (T13): only rescale when some lane's max grew by > 8 (exp2 units)
        if (!__all(tmax <= mrow[nq] + 8.0f)) {
          const float mnew = fmaxf(mrow[nq], tmax);
          const float resc = __builtin_amdgcn_exp2f(mrow[nq] - mnew);
          mrow[nq] = mnew;
          lrow[nq] *= resc;
#pragma unroll
          for (int mtd = 0; mtd < 4; ++mtd) ctx[mtd][nq] = ctx[mtd][nq] * resc;
        }
        const float mcur = mrow[nq];
#pragma unroll
        for (int mt = 0; mt < 4; ++mt)
#pragma unroll
          for (int r = 0; r < 4; ++r)
            p[mt][r] = __builtin_amdgcn_exp2f(p[mt][r] - mcur);
        // sum tree
        float s0 = (p[0][0] + p[0][1]) + (p[0][2] + p[0][3]);
        float s1 = (p[1][0] + p[1][1]) + (p[1][2] + p[1][3]);
        float s2 = (p[2][0] + p[2][1]) + (p[2][2] + p[2][3]);
        float s3 = (p[3][0] + p[3][1]) + (p[3][2] + p[3][3]);
        float psum = (s0 + s1) + (s2 + s3);
        psum += __shfl_xor(psum, 16, 64);
        psum += __shfl_xor(psum, 32, 64);
        lrow[nq] += psum;
        // pack P for PV (plain casts -> v_cvt_pk_bf16_f32)
#pragma unroll
        for (int ks2 = 0; ks2 < 2; ++ks2) {
          union { __bf16 b[8]; bf16x8 v; } u;
#pragma unroll
          for (int r = 0; r < 4; ++r) {
            u.b[r] = (__bf16)p[2 * ks2][r];
            u.b[4 + r] = (__bf16)p[2 * ks2 + 1][r];
          }
          pb[nq][ks2] = u.v;
        }
      }

      // ---- PV: ctx^T[d][q] += Vt . P^T  (pi-permuted k; A = 2x ds_read_b64) ----
#pragma unroll
      for (int ks2 = 0; ks2 < 2; ++ks2)
#pragma unroll
        for (int mtd = 0; mtd < 4; ++mtd) {
          const int rd = mtd * 16 + li;
          const char* vb = ldsc + 8192 + rd * 128;
          const uint2 lo = *(const uint2*)(vb + (((ks2 * 4 + (g >> 1)) ^ (rd & 7)) * 16) + (g & 1) * 8);
          const uint2 hi = *(const uint2*)(vb + (((ks2 * 4 + 2 + (g >> 1)) ^ (rd & 7)) * 16) + (g & 1) * 8);
          uint4 vv; vv.x = lo.x; vv.y = lo.y; vv.z = hi.x; vv.w = hi.y;
          const bf16x8 vf = __builtin_bit_cast(bf16x8, vv);
#pragma unroll
          for (int nq = 0; nq < 2; ++nq)
            ctx[mtd][nq] = __builtin_amdgcn_mfma_f32_16x16x32_bf16(vf, pb[nq][ks2], ctx[mtd][nq], 0, 0, 0);
        }
    }

    // ---- epilogue: ctx^T -> ctx via per-wave swizzled LDS (reuses K/V region) ----
    __syncthreads();
    float* trb = (float*)(ldsc + wv * 8192);
#pragma unroll
    for (int nq = 0; nq < 2; ++nq) {
      const float inv = 1.0f / lrow[nq];
      const int q = nq * 16 + li;
#pragma unroll
      for (int mtd = 0; mtd < 4; ++mtd)
#pragma unroll
        for (int r = 0; r < 4; ++r) {
          const int d = mtd * 16 + g * 4 + r;
          trb[q * 64 + ((((d >> 2) ^ (q & 15)) << 2) | (d & 3))] = ctx[mtd][nq][r] * inv;
        }
    }
    __syncthreads();
#pragma unroll
    for (int pass = 0; pass < 8; ++pass) {
      const int qr = pass * 4 + g;
      const float4 v = *(const float4*)&trb[qr * 64 + ((li ^ (qr & 15)) << 2)];
      *(float4*)(out + ((size_t)bI * 2048 + q0 + wv * 32 + qr) * 1024 + h * 64 + li * 4) = v;
    }
    __syncthreads();  // epilogue reads done before next half's staging writes
  }
}

// ---------------- launcher ----------------
extern "C" void kernel_launch(void* const* d_in, const int* in_sizes, int n_in,
                              void* d_out, int out_size, void* d_ws, size_t ws_size,
                              hipStream_t stream) {
  (void)in_sizes; (void)n_in; (void)out_size; (void)ws_size;
  const float* x  = (const float*)d_in[0];
  const float* Wq = (const float*)d_in[1];
  const float* Wk = (const float*)d_in[2];
  const float* Wv = (const float*)d_in[3];
  float* out = (float*)d_out;
  char* ws = (char*)d_ws;
  unsigned short* xb  = (unsigned short*)ws;                    // 8192x1024 bf16  (16 MB)
  unsigned short* Wt  = (unsigned short*)(ws + 16777216);       // 3x 1024x1024 bf16 (6 MB)
  unsigned short* Qb  = (unsigned short*)(ws + 23068672);       // [64][2048][64] bf16
  unsigned short* Kb  = (unsigned short*)(ws + 39845888);       // [64][2048][64] bf16
  unsigned short* Vtb = (unsigned short*)(ws + 56623104);       // [64][64][2048] bf16

  hipLaunchKernelGGL(cvt_x_kernel, dim3(4096), dim3(256), 0, stream, x, xb);
  hipLaunchKernelGGL(wt_kernel, dim3(32, 32, 3), dim3(32, 8), 0, stream, Wq, Wk, Wv, Wt);
  hipLaunchKernelGGL(gemm_qkv, dim3(8, 64, 3), dim3(256), 0, stream, xb, Wt, Qb, Kb, Vtb);
  hipLaunchKernelGGL(attn_kernel, dim3(8, 64), dim3(256), 0, stream, Qb, Kb, Vtb, out);
}